// Round 3
// baseline (214.350 us; speedup 1.0000x reference)
//
#include <hip/hip_runtime.h>

// B=2, T=2048, C=1024, H=16, D=64. Inputs fp32, OUTPUT fp32.
// Round 15:
//  - flash_k: per-lane l partials (no per-tile sum shuffles; fold once at
//    end), defer-max guard on per-lane LOCAL max (cross-lane max reduce only
//    on update tiles), P-pack via v_cvt_pk_bf16_f32 (2 instr / 4 vals).
//  - qkv_rope_k / proj_k: LDS padding dropped (linear [128][64]),
//    global->LDS staging via __builtin_amdgcn_global_load_lds width=16
//    (m97 structure; dest = wave-uniform base + lane*16 exactly).
// Rest = round 14 (512-thread flash, dbuf K/V, base-2 softmax, one barrier).
// MFMA 16x16x32_bf16 layouts (HW-verified): A: m=lane&15,k=quad*8+j;
// B: k=quad*8+j,n=lane&15; C/D: col=lane&15,row=quad*4+reg.

typedef unsigned short u16;
typedef u16 u16x4 __attribute__((ext_vector_type(4)));
typedef u16 u16x8 __attribute__((ext_vector_type(8)));
typedef short s16x8 __attribute__((ext_vector_type(8)));
typedef float f32x4 __attribute__((ext_vector_type(4)));

#define T_SEQ 2048
#define C_EMB 1024
#define NH 16
#define HD 64

#define MFMA16(a, b, c) __builtin_amdgcn_mfma_f32_16x16x32_bf16(a, b, c, 0, 0, 0)

__device__ __forceinline__ u16 f2bf(float f) {
    union { float f; unsigned int i; } x; x.f = f;
    unsigned int r = x.i + 0x7fffu + ((x.i >> 16) & 1u);
    return (u16)(r >> 16);
}
__device__ __forceinline__ u16x4 pack4(f32x4 v) {
    u16x4 o;
#pragma unroll
    for (int j = 0; j < 4; ++j) o[j] = f2bf(v[j]);
    return o;
}
// hot-loop pack: HW packed convert (RNE), 2 instr per 4 values
__device__ __forceinline__ u16x4 pack4cvt(f32x4 v) {
    union { u16x4 h; unsigned int w[2]; } u;
    asm("v_cvt_pk_bf16_f32 %0, %1, %2" : "=v"(u.w[0]) : "v"(v[0]), "v"(v[1]));
    asm("v_cvt_pk_bf16_f32 %0, %1, %2" : "=v"(u.w[1]) : "v"(v[2]), "v"(v[3]));
    return u.h;
}
// async global->LDS, 16B per lane (dest must be wave-uniform base + lane*16)
__device__ __forceinline__ void gload16(const void* g, void* l) {
    __builtin_amdgcn_global_load_lds(
        (const __attribute__((address_space(1))) unsigned int*)g,
        (__attribute__((address_space(3))) unsigned int*)l, 16, 0, 0);
}

// ---------------- k0a: fp32 -> bf16 convert ----------------
__global__ __launch_bounds__(256) void conv_k(const float* __restrict__ src, u16* __restrict__ dst, int n8) {
    int i = blockIdx.x * 256 + threadIdx.x;
    if (i >= n8) return;
    f32x4 a = ((const f32x4*)src)[i * 2];
    f32x4 b = ((const f32x4*)src)[i * 2 + 1];
    u16x8 o;
#pragma unroll
    for (int j = 0; j < 4; ++j) o[j] = f2bf(a[j]);
#pragma unroll
    for (int j = 0; j < 4; ++j) o[4 + j] = f2bf(b[j]);
    ((u16x8*)dst)[i] = o;
}

// ---------------- k0b: rope tables ----------------
__global__ __launch_bounds__(256) void rope_tab_k(float2* __restrict__ tab) {
    int idx = blockIdx.x * 256 + threadIdx.x;   // 65536 = T*32
    int t = idx >> 5, j = idx & 31;
    float inv = __builtin_exp2f(-0.41524101186092f * (float)j);  // 10000^(-j/32)
    float s_, c_;
    sincosf((float)t * inv, &s_, &c_);
    tab[idx] = make_float2(c_, s_);
}

// ---------------- k1: QKV GEMM + RoPE (MFMA, bf16, global_load_lds) --------
// grid (24, 32): n0 = bx*128 (0..3071), m0 = by*128 (0..4095)
__global__ __launch_bounds__(256) void qkv_rope_k(const u16* __restrict__ xb, const u16* __restrict__ Wab,
                                                  const float* __restrict__ bias,
                                                  const float2* __restrict__ tab,
                                                  u16* __restrict__ qb, u16* __restrict__ kb,
                                                  u16* __restrict__ vt) {
    __shared__ u16 smem[17408];               // As[8192] | Bs[8192]; epilogue Ct[17408]
    u16* As = smem;                           // [128][64] linear
    u16* Bs = smem + 8192;                    // [128][64] linear
    int tid = threadIdx.x;
    int n0 = blockIdx.x * 128, m0 = blockIdx.y * 128;
    int w = tid >> 6, lane = tid & 63, lr = lane & 15, quad = lane >> 4;
    int wr = w >> 1, wc = w & 1;
    f32x4 acc[4][4] = {};
    int srow = tid >> 3, sc8 = (tid & 7) << 3;  // idx = it*256+tid -> row=idx>>3
    for (int kt = 0; kt < C_EMB; kt += 64) {
#pragma unroll
        for (int it = 0; it < 4; ++it) {
            int row = it * 32 + srow;          // (it*256+tid)>>3
            int off = (it * 256 + tid) * 8;    // u16 LDS offset = idx*8
            gload16(xb + (size_t)(m0 + row) * C_EMB + kt + sc8, &As[off]);
            gload16(Wab + (size_t)(n0 + row) * C_EMB + kt + sc8, &Bs[off]);
        }
        __syncthreads();
#pragma unroll
        for (int ks = 0; ks < 64; ks += 32) {
            s16x8 af[4], bf[4];
#pragma unroll
            for (int i = 0; i < 4; ++i)
                af[i] = *(const s16x8*)&As[(wr * 64 + i * 16 + lr) * 64 + ks + quad * 8];
#pragma unroll
            for (int j = 0; j < 4; ++j)
                bf[j] = *(const s16x8*)&Bs[(wc * 64 + j * 16 + lr) * 64 + ks + quad * 8];
#pragma unroll
            for (int i = 0; i < 4; ++i)
#pragma unroll
                for (int j = 0; j < 4; ++j) acc[i][j] = MFMA16(af[i], bf[j], acc[i][j]);
        }
        __syncthreads();
    }
    int sec = n0 >> 10;                       // 0=q 1=k 2=v (blocks never straddle)
    float bv[4];
#pragma unroll
    for (int j = 0; j < 4; ++j) bv[j] = bias[n0 + wc * 64 + j * 16 + lr];

    int h0 = (n0 & 1023) >> 6;
    int b = m0 >> 11, tbase = m0 & 2047;
    if (sec == 2) {
        // C tile (+bias) -> LDS [d][m] (136-padded) -> coalesced 16B
        // transposed stores to vt[((b*16+h)*64+d)*2048 + t].
        u16* Ct = smem;                        // 128 x 136 u16 = 34816 B
#pragma unroll
        for (int i = 0; i < 4; ++i)
#pragma unroll
            for (int j = 0; j < 4; ++j) {
                f32x4 vv;
#pragma unroll
                for (int r = 0; r < 4; ++r) vv[r] = acc[i][j][r] + bv[j];
                int d = wc * 64 + j * 16 + lr;
                int m4 = wr * 64 + i * 16 + quad * 4;
                *(u16x4*)&Ct[d * 136 + m4] = pack4(vv);
            }
        __syncthreads();
        size_t hb = (size_t)(b * NH);
#pragma unroll
        for (int p = 0; p < 8; ++p) {
            int idx = p * 256 + tid;
            int d = idx >> 4, mc = (idx & 15) << 3;
            s16x8 vdat = *(const s16x8*)&Ct[d * 136 + mc];
            int h = h0 + (d >> 6), dd = d & 63;
            *(s16x8*)(vt + ((hb + h) * HD + dd) * T_SEQ + tbase + mc) = vdat;
        }
    } else {
        // q/k: RoPE in-register, stage [m][n] in LDS, coalesced b128 stores.
        u16* dst = (sec == 0) ? qb : kb;
        // fold 1/sqrt(D) AND log2(e) into q so flash softmax is native base-2:
        float qs = (sec == 0) ? 0.18033688011112043f : 1.0f;
        u16* Ct = smem;                        // 128 x 136 u16
#pragma unroll
        for (int i = 0; i < 4; ++i)
#pragma unroll
            for (int r = 0; r < 4; ++r) {
                int mrow = wr * 64 + i * 16 + quad * 4 + r;
                int t = (m0 + mrow) & 2047;
#pragma unroll
                for (int j = 0; j < 2; ++j) {
                    int d1 = j * 16 + lr;                 // 0..31; partner +32 in tile j+2
                    float2 cs = tab[t * 32 + d1];
                    float v1 = acc[i][j][r] + bv[j];
                    float v2 = acc[i][j + 2][r] + bv[j + 2];
                    int n1 = wc * 64 + j * 16 + lr;
                    Ct[mrow * 136 + n1]      = f2bf((v1 * cs.x - v2 * cs.y) * qs);
                    Ct[mrow * 136 + n1 + 32] = f2bf((v2 * cs.x + v1 * cs.y) * qs);
                }
            }
        __syncthreads();
#pragma unroll
        for (int p = 0; p < 8; ++p) {
            int idx = p * 256 + tid;              // 128 rows x 16 chunks of 8 u16
            int mrow = idx >> 4, c = idx & 15;
            s16x8 vdat = *(const s16x8*)&Ct[mrow * 136 + c * 8];
            int h = h0 + (c >> 3), dd = (c & 7) << 3;
            *(s16x8*)(dst + ((size_t)(b * NH + h) * T_SEQ + tbase + mrow) * HD + dd) = vdat;
        }
    }
}

// ---------------- k2: flash attention (MFMA, S^T/O^T form) ----------------
// grid (16, 32), 512 threads / 8 waves. 128-row Q tile; wave w owns the ONE
// strip at rows [q0+16w, +16). All 512 blocks co-resident (2/CU, 16 waves/CU).
// S^T tile: elem (k' = k0+tc*16+quad*4+r, q = rbase+lr) — lane owns q-row lr.
// Double-buffered K/V LDS, one barrier per k-tile. Softmax: per-lane l
// partials (no per-tile sum shuffles), defer-max guard on per-lane local max
// (cross-lane max only on update tiles), cvt_pk bf16 pack.
__global__ __launch_bounds__(512, 4) void flash_k(const u16* __restrict__ qb, const u16* __restrict__ kb,
                                                  const u16* __restrict__ vt, u16* __restrict__ yab) {
    __shared__ u16 Ks[2][64 * 72];
    __shared__ u16 Vs[2][64 * 72];
    __shared__ u16 Ps[8][16 * 72];           // [wave][q-row 16][k' 64 pad 72]
    int tid = threadIdx.x;
    int bx = blockIdx.x, by = blockIdx.y;
    int qt = (by < 16) ? (15 - bx) : bx;      // complementary pairing for balance
    int bh = by;
    int w = tid >> 6, lane = tid & 63, lr = lane & 15, quad = lane >> 4;
    int q0 = qt * 128;
    const u16* qh = qb + (size_t)bh * T_SEQ * HD;
    const u16* kh = kb + (size_t)bh * T_SEQ * HD;
    const u16* vh = vt + (size_t)bh * HD * T_SEQ;

    int rbase = q0 + w * 16;                  // this wave's strip

    s16x8 aq[2];                              // B-frag of Q (n=q-row=lr, k=d)
#pragma unroll
    for (int ks = 0; ks < 2; ++ks)
        aq[ks] = *(const s16x8*)(qh + (size_t)(rbase + lr) * HD + ks * 32 + quad * 8);

    int srow = tid >> 3, sc8 = (tid & 7) << 3;   // staging coords: rows 0..63

    float m_i = -1e30f;
    f32x4 l4 = {0.f, 0.f, 0.f, 0.f};          // per-lane l partials
    f32x4 oacc[4] = {};                       // O^T: elem (d=tn*16+quad*4+r, q=lr)

    int ktmax = 2 * qt + 1;
    {   // prologue: stage tile 0 into buffer 0 (1 K-row + 1 V-row per thread)
        s16x8 kr0 = *(const s16x8*)(kh + (size_t)srow * HD + sc8);
        s16x8 vr0 = *(const s16x8*)(vh + (size_t)srow * T_SEQ + sc8);
        *(s16x8*)&Ks[0][srow * 72 + sc8] = kr0;
        *(s16x8*)&Vs[0][srow * 72 + sc8] = vr0;
    }
    __syncthreads();

    for (int kt = 0; kt <= ktmax; ++kt) {
        int cur = kt & 1;
        int k0 = kt * 64;
        bool pf = kt < ktmax;
        s16x8 kr0, vr0;                       // next-tile prefetch registers
        if (pf) {
            int kn = k0 + 64;
            kr0 = *(const s16x8*)(kh + (size_t)(kn + srow) * HD + sc8);
            vr0 = *(const s16x8*)(vh + (size_t)srow * T_SEQ + kn + sc8);
        }
        const u16* Kc = Ks[cur];
        const u16* Vc = Vs[cur];

        if (k0 <= rbase + 15) {               // strip not fully above diagonal
            s16x8 ak[2][4], av[2][4];         // K frag (m=k-row=lr) / V frag (m=d=lr)
#pragma unroll
            for (int ks = 0; ks < 2; ++ks)
#pragma unroll
                for (int tc = 0; tc < 4; ++tc) {
                    ak[ks][tc] = *(const s16x8*)&Kc[(tc * 16 + lr) * 72 + ks * 32 + quad * 8];
                    av[ks][tc] = *(const s16x8*)&Vc[(tc * 16 + lr) * 72 + ks * 32 + quad * 8];
                }
            f32x4 sacc[4] = {};
#pragma unroll
            for (int ks = 0; ks < 2; ++ks)
#pragma unroll
                for (int tc = 0; tc < 4; ++tc) sacc[tc] = MFMA16(ak[ks][tc], aq[ks], sacc[tc]);
            if (k0 + 63 > rbase) {
#pragma unroll
                for (int tc = 0; tc < 4; ++tc)
#pragma unroll
                    for (int r = 0; r < 4; ++r)
                        if (k0 + tc * 16 + quad * 4 + r > rbase + lr) sacc[tc][r] = -1e30f;
            }
            // per-lane local max (row max = max over 4 lanes; __all is the
            // same condition as the old row-max guard)
            f32x4 mv = sacc[0];
#pragma unroll
            for (int tc = 1; tc < 4; ++tc)
#pragma unroll
                for (int r = 0; r < 4; ++r) mv[r] = fmaxf(mv[r], sacc[tc][r]);
            float loc = fmaxf(fmaxf(mv[0], mv[1]), fmaxf(mv[2], mv[3]));
            bool need = !__all(loc <= m_i + 8.0f);   // defer-max (T13, THR=8)
            float alpha = 1.0f;
            if (need) {                        // rare: full cross-lane max
                float mx = fmaxf(loc, __shfl_xor(loc, 16, 64));
                mx = fmaxf(mx, __shfl_xor(mx, 32, 64));
                float mn = fmaxf(m_i, mx);
                alpha = __builtin_exp2f(m_i - mn);
                m_i = mn;
#pragma unroll
                for (int r = 0; r < 4; ++r) l4[r] *= alpha;
            }
            float mnow = m_i;
#pragma unroll
            for (int tc = 0; tc < 4; ++tc)
#pragma unroll
                for (int r = 0; r < 4; ++r) {
                    float p = __builtin_exp2f(sacc[tc][r] - mnow);
                    sacc[tc][r] = p;
                    l4[r] += p;                // per-lane partial; folded at end
                }
            // P^T -> LDS [q][k'] (cvt_pk packed 8B writes)
#pragma unroll
            for (int tc = 0; tc < 4; ++tc)
                *(u16x4*)&Ps[w][lr * 72 + tc * 16 + quad * 4] = pack4cvt(sacc[tc]);
            if (need) {
#pragma unroll
                for (int tn = 0; tn < 4; ++tn)
#pragma unroll
                    for (int r = 0; r < 4; ++r) oacc[tn][r] *= alpha;
            }
#pragma unroll
            for (int ks = 0; ks < 2; ++ks) {
                s16x8 ap = *(const s16x8*)&Ps[w][lr * 72 + ks * 32 + quad * 8];
#pragma unroll
                for (int tn = 0; tn < 4; ++tn) oacc[tn] = MFMA16(av[ks][tn], ap, oacc[tn]);
            }
        }
        if (pf) {                              // write prefetched tile to other buffer
            int nx = cur ^ 1;
            *(s16x8*)&Ks[nx][srow * 72 + sc8] = kr0;
            *(s16x8*)&Vs[nx][srow * 72 + sc8] = vr0;
        }
        __syncthreads();                       // single barrier per k-tile
    }
    // fold l partials: 4 per-lane + the 4 lanes of each row (xor 16, 32)
    float rs = (l4[0] + l4[1]) + (l4[2] + l4[3]);
    rs += __shfl_xor(rs, 16, 64);
    rs += __shfl_xor(rs, 32, 64);
    int b = bh >> 4, hh = bh & 15;
    {
        float inv = 1.f / rs;
        int t = rbase + lr;
        size_t base = ((size_t)b * T_SEQ + t) * C_EMB + hh * HD;
#pragma unroll
        for (int tn = 0; tn < 4; ++tn) {
            f32x4 vv;
#pragma unroll
            for (int r = 0; r < 4; ++r) vv[r] = oacc[tn][r] * inv;
            *(u16x4*)(yab + base + tn * 16 + quad * 4) = pack4(vv);
        }
    }
}

// ---------------- k3: output projection (MFMA, bf16, global_load_lds) ------
// grid (8, 32): n0 = bx*128 (0..1023), m0 = by*128
__global__ __launch_bounds__(256) void proj_k(const u16* __restrict__ ya, const u16* __restrict__ Wpb,
                                              const float* __restrict__ bias, float* __restrict__ out) {
    __shared__ u16 As[8192];                  // [128][64] linear
    __shared__ u16 Bs[8192];
    int tid = threadIdx.x;
    int n0 = blockIdx.x * 128, m0 = blockIdx.y * 128;
    int w = tid >> 6, lane = tid & 63, lr = lane & 15, quad = lane >> 4;
    int wr = w >> 1, wc = w & 1;
    f32x4 acc[4][4] = {};
    int srow = tid >> 3, sc8 = (tid & 7) << 3;
    for (int kt = 0; kt < C_EMB; kt += 64) {
#pragma unroll
        for (int it = 0; it < 4; ++it) {
            int row = it * 32 + srow;
            int off = (it * 256 + tid) * 8;
            gload16(ya + (size_t)(m0 + row) * C_EMB + kt + sc8, &As[off]);
            gload16(Wpb + (size_t)(n0 + row) * C_EMB + kt + sc8, &Bs[off]);
        }
        __syncthreads();
#pragma unroll
        for (int ks = 0; ks < 64; ks += 32) {
            s16x8 af[4], bf[4];
#pragma unroll
            for (int i = 0; i < 4; ++i)
                af[i] = *(const s16x8*)&As[(wr * 64 + i * 16 + lr) * 64 + ks + quad * 8];
#pragma unroll
            for (int j = 0; j < 4; ++j)
                bf[j] = *(const s16x8*)&Bs[(wc * 64 + j * 16 + lr) * 64 + ks + quad * 8];
#pragma unroll
            for (int i = 0; i < 4; ++i)
#pragma unroll
                for (int j = 0; j < 4; ++j) acc[i][j] = MFMA16(af[i], bf[j], acc[i][j]);
        }
        __syncthreads();
    }
    float bv[4];
#pragma unroll
    for (int j = 0; j < 4; ++j) bv[j] = bias[n0 + wc * 64 + j * 16 + lr];
#pragma unroll
    for (int i = 0; i < 4; ++i)
#pragma unroll
        for (int r = 0; r < 4; ++r) {
            int m = m0 + wr * 64 + i * 16 + quad * 4 + r;
#pragma unroll
            for (int j = 0; j < 4; ++j)
                out[(size_t)m * C_EMB + n0 + wc * 64 + j * 16 + lr] = acc[i][j][r] + bv[j];
        }
}

extern "C" void kernel_launch(void* const* d_in, const int* in_sizes, int n_in,
                              void* d_out, int out_size, void* d_ws, size_t ws_size,
                              hipStream_t stream) {
    // Inputs resolved BY ELEMENT COUNT (unique): x 4194304, W_attn 3145728,
    // b_attn 3072, W_proj 1048576, b_proj 1024. All fp32.
    const float *x = nullptr, *Wa = nullptr, *ba = nullptr, *Wp = nullptr, *bp = nullptr;
    for (int i = 0; i < n_in; ++i) {
        switch (in_sizes[i]) {
            case 4194304: x  = (const float*)d_in[i]; break;
            case 3145728: Wa = (const float*)d_in[i]; break;
            case 3072:    ba = (const float*)d_in[i]; break;
            case 1048576: Wp = (const float*)d_in[i]; break;
            case 1024:    bp = (const float*)d_in[i]; break;
            default: break;
        }
    }
    float* out = (float*)d_out;

    char* ws = (char*)d_ws;
    u16* qb     = (u16*)(ws);                    //  0.. 8 MiB  bf16 [B,H,T,D] (q*0.125*log2e)
    u16* kb     = (u16*)(ws + 8388608);          //  8..16 MiB  bf16 [B,H,T,D]
    u16* vt     = (u16*)(ws + 16777216);         // 16..24 MiB  bf16 [B,H,D,T]
    u16* yab    = (u16*)(ws + 25165824);         // 24..32 MiB  bf16 [B,T,C]
    float2* tab = (float2*)(ws + 33554432);      // 32..32.5 MiB
    u16* xb     = (u16*)(ws + 35651584);         // 34..42 MiB  bf16 [4096,1024]
    u16* Wab    = (u16*)(ws + 44040192);         // 42..48 MiB  bf16 [3072,1024]
    u16* Wpb    = (u16*)(ws + 50331648);         // 48..50 MiB  bf16 [1024,1024]

    conv_k<<<2048, 256, 0, stream>>>(x, xb, 524288);
    conv_k<<<1536, 256, 0, stream>>>(Wa, Wab, 393216);
    conv_k<<<512, 256, 0, stream>>>(Wp, Wpb, 131072);
    rope_tab_k<<<256, 256, 0, stream>>>(tab);
    qkv_rope_k<<<dim3(24, 32), 256, 0, stream>>>(xb, Wab, ba, tab, qb, kb, vt);
    flash_k<<<dim3(16, 32), 512, 0, stream>>>(qb, kb, vt, yab);
    proj_k<<<dim3(8, 32), 256, 0, stream>>>(yab, Wpb, bp, out);
}

// Round 4
// 203.589 us; speedup vs baseline: 1.0529x; 1.0529x over previous
//
#include <hip/hip_runtime.h>

// B=2, T=2048, C=1024, H=16, D=64. Inputs fp32, OUTPUT fp32.
// Round 16: fix R15's bank-conflict regression in qkv_rope_k/proj_k.
// Linear [128][64] LDS (128B row stride) made all 16 fragment rows alias one
// 16B slot (16-way). Per rule #21 (both-sides-or-neither with gload_lds):
// keep linear LDS dest, PRE-SWIZZLE the global source column
// (slot ^= row&7 within each 128B row) and apply the same XOR on the
// fragment reads. Post-fix aliasing = 8 lanes/slot = b128 HW minimum.
// flash_k unchanged from R15 (per-lane l partials, local-max defer guard,
// cvt_pk pack, dbuf K/V, one barrier/tile, 512 thr).
// MFMA 16x16x32_bf16 layouts (HW-verified): A: m=lane&15,k=quad*8+j;
// B: k=quad*8+j,n=lane&15; C/D: col=lane&15,row=quad*4+reg.

typedef unsigned short u16;
typedef u16 u16x4 __attribute__((ext_vector_type(4)));
typedef u16 u16x8 __attribute__((ext_vector_type(8)));
typedef short s16x8 __attribute__((ext_vector_type(8)));
typedef float f32x4 __attribute__((ext_vector_type(4)));

#define T_SEQ 2048
#define C_EMB 1024
#define NH 16
#define HD 64

#define MFMA16(a, b, c) __builtin_amdgcn_mfma_f32_16x16x32_bf16(a, b, c, 0, 0, 0)

__device__ __forceinline__ u16 f2bf(float f) {
    union { float f; unsigned int i; } x; x.f = f;
    unsigned int r = x.i + 0x7fffu + ((x.i >> 16) & 1u);
    return (u16)(r >> 16);
}
__device__ __forceinline__ u16x4 pack4(f32x4 v) {
    u16x4 o;
#pragma unroll
    for (int j = 0; j < 4; ++j) o[j] = f2bf(v[j]);
    return o;
}
// hot-loop pack: HW packed convert (RNE), 2 instr per 4 values
__device__ __forceinline__ u16x4 pack4cvt(f32x4 v) {
    union { u16x4 h; unsigned int w[2]; } u;
    asm("v_cvt_pk_bf16_f32 %0, %1, %2" : "=v"(u.w[0]) : "v"(v[0]), "v"(v[1]));
    asm("v_cvt_pk_bf16_f32 %0, %1, %2" : "=v"(u.w[1]) : "v"(v[2]), "v"(v[3]));
    return u.h;
}
// async global->LDS, 16B per lane (dest must be wave-uniform base + lane*16)
__device__ __forceinline__ void gload16(const void* g, void* l) {
    __builtin_amdgcn_global_load_lds(
        (const __attribute__((address_space(1))) unsigned int*)g,
        (__attribute__((address_space(3))) unsigned int*)l, 16, 0, 0);
}

// ---------------- k0a: fp32 -> bf16 convert ----------------
__global__ __launch_bounds__(256) void conv_k(const float* __restrict__ src, u16* __restrict__ dst, int n8) {
    int i = blockIdx.x * 256 + threadIdx.x;
    if (i >= n8) return;
    f32x4 a = ((const f32x4*)src)[i * 2];
    f32x4 b = ((const f32x4*)src)[i * 2 + 1];
    u16x8 o;
#pragma unroll
    for (int j = 0; j < 4; ++j) o[j] = f2bf(a[j]);
#pragma unroll
    for (int j = 0; j < 4; ++j) o[4 + j] = f2bf(b[j]);
    ((u16x8*)dst)[i] = o;
}

// ---------------- k0b: rope tables ----------------
__global__ __launch_bounds__(256) void rope_tab_k(float2* __restrict__ tab) {
    int idx = blockIdx.x * 256 + threadIdx.x;   // 65536 = T*32
    int t = idx >> 5, j = idx & 31;
    float inv = __builtin_exp2f(-0.41524101186092f * (float)j);  // 10000^(-j/32)
    float s_, c_;
    sincosf((float)t * inv, &s_, &c_);
    tab[idx] = make_float2(c_, s_);
}

// ---------------- k1: QKV GEMM + RoPE (MFMA, bf16, gload_lds + XOR swz) ----
// grid (24, 32): n0 = bx*128 (0..3071), m0 = by*128 (0..4095)
// LDS tile [128][8 slots of 16B]; LDS[row][slot] holds global col-slot
// (slot ^ (row&7)). Staging pre-swizzles the SOURCE col; reads XOR the slot.
__global__ __launch_bounds__(256) void qkv_rope_k(const u16* __restrict__ xb, const u16* __restrict__ Wab,
                                                  const float* __restrict__ bias,
                                                  const float2* __restrict__ tab,
                                                  u16* __restrict__ qb, u16* __restrict__ kb,
                                                  u16* __restrict__ vt) {
    __shared__ u16 smem[17408];               // As[8192] | Bs[8192]; epilogue Ct[17408]
    u16* As = smem;                           // [128][64] linear (content swizzled)
    u16* Bs = smem + 8192;
    int tid = threadIdx.x;
    int n0 = blockIdx.x * 128, m0 = blockIdx.y * 128;
    int w = tid >> 6, lane = tid & 63, lr = lane & 15, quad = lane >> 4;
    int wr = w >> 1, wc = w & 1;
    f32x4 acc[4][4] = {};
    int srow = tid >> 3;                                  // staging row (0..31 per it)
    int swc8 = (((tid & 7) ^ (srow & 7)) << 3);           // pre-swizzled src col (u16)
    int lrx = lr & 7;                                     // fragment-read XOR key
    for (int kt = 0; kt < C_EMB; kt += 64) {
#pragma unroll
        for (int it = 0; it < 4; ++it) {
            int row = it * 32 + srow;          // (it*256+tid)>>3  (row&7 == srow&7)
            int off = (it * 256 + tid) * 8;    // linear u16 LDS offset = idx*8
            gload16(xb + (size_t)(m0 + row) * C_EMB + kt + swc8, &As[off]);
            gload16(Wab + (size_t)(n0 + row) * C_EMB + kt + swc8, &Bs[off]);
        }
        __syncthreads();
#pragma unroll
        for (int ks = 0; ks < 64; ks += 32) {
            int slot = (ks >> 3) + quad;                   // 0..7
            int rc8 = ((slot ^ lrx) << 3);                 // swizzled read col (u16)
            s16x8 af[4], bf[4];
#pragma unroll
            for (int i = 0; i < 4; ++i)
                af[i] = *(const s16x8*)&As[(wr * 64 + i * 16 + lr) * 64 + rc8];
#pragma unroll
            for (int j = 0; j < 4; ++j)
                bf[j] = *(const s16x8*)&Bs[(wc * 64 + j * 16 + lr) * 64 + rc8];
#pragma unroll
            for (int i = 0; i < 4; ++i)
#pragma unroll
                for (int j = 0; j < 4; ++j) acc[i][j] = MFMA16(af[i], bf[j], acc[i][j]);
        }
        __syncthreads();
    }
    int sec = n0 >> 10;                       // 0=q 1=k 2=v (blocks never straddle)
    float bv[4];
#pragma unroll
    for (int j = 0; j < 4; ++j) bv[j] = bias[n0 + wc * 64 + j * 16 + lr];

    int h0 = (n0 & 1023) >> 6;
    int b = m0 >> 11, tbase = m0 & 2047;
    if (sec == 2) {
        // C tile (+bias) -> LDS [d][m] (136-padded) -> coalesced 16B
        // transposed stores to vt[((b*16+h)*64+d)*2048 + t].
        u16* Ct = smem;                        // 128 x 136 u16 = 34816 B
#pragma unroll
        for (int i = 0; i < 4; ++i)
#pragma unroll
            for (int j = 0; j < 4; ++j) {
                f32x4 vv;
#pragma unroll
                for (int r = 0; r < 4; ++r) vv[r] = acc[i][j][r] + bv[j];
                int d = wc * 64 + j * 16 + lr;
                int m4 = wr * 64 + i * 16 + quad * 4;
                *(u16x4*)&Ct[d * 136 + m4] = pack4(vv);
            }
        __syncthreads();
        size_t hb = (size_t)(b * NH);
#pragma unroll
        for (int p = 0; p < 8; ++p) {
            int idx = p * 256 + tid;
            int d = idx >> 4, mc = (idx & 15) << 3;
            s16x8 vdat = *(const s16x8*)&Ct[d * 136 + mc];
            int h = h0 + (d >> 6), dd = d & 63;
            *(s16x8*)(vt + ((hb + h) * HD + dd) * T_SEQ + tbase + mc) = vdat;
        }
    } else {
        // q/k: RoPE in-register, stage [m][n] in LDS, coalesced b128 stores.
        u16* dst = (sec == 0) ? qb : kb;
        // fold 1/sqrt(D) AND log2(e) into q so flash softmax is native base-2:
        float qs = (sec == 0) ? 0.18033688011112043f : 1.0f;
        u16* Ct = smem;                        // 128 x 136 u16
#pragma unroll
        for (int i = 0; i < 4; ++i)
#pragma unroll
            for (int r = 0; r < 4; ++r) {
                int mrow = wr * 64 + i * 16 + quad * 4 + r;
                int t = (m0 + mrow) & 2047;
#pragma unroll
                for (int j = 0; j < 2; ++j) {
                    int d1 = j * 16 + lr;                 // 0..31; partner +32 in tile j+2
                    float2 cs = tab[t * 32 + d1];
                    float v1 = acc[i][j][r] + bv[j];
                    float v2 = acc[i][j + 2][r] + bv[j + 2];
                    int n1 = wc * 64 + j * 16 + lr;
                    Ct[mrow * 136 + n1]      = f2bf((v1 * cs.x - v2 * cs.y) * qs);
                    Ct[mrow * 136 + n1 + 32] = f2bf((v2 * cs.x + v1 * cs.y) * qs);
                }
            }
        __syncthreads();
#pragma unroll
        for (int p = 0; p < 8; ++p) {
            int idx = p * 256 + tid;              // 128 rows x 16 chunks of 8 u16
            int mrow = idx >> 4, c = idx & 15;
            s16x8 vdat = *(const s16x8*)&Ct[mrow * 136 + c * 8];
            int h = h0 + (c >> 3), dd = (c & 7) << 3;
            *(s16x8*)(dst + ((size_t)(b * NH + h) * T_SEQ + tbase + mrow) * HD + dd) = vdat;
        }
    }
}

// ---------------- k2: flash attention (MFMA, S^T/O^T form) ----------------
// grid (16, 32), 512 threads / 8 waves. 128-row Q tile; wave w owns the ONE
// strip at rows [q0+16w, +16). All 512 blocks co-resident (2/CU, 16 waves/CU).
// S^T tile: elem (k' = k0+tc*16+quad*4+r, q = rbase+lr) — lane owns q-row lr.
// Double-buffered K/V LDS, one barrier per k-tile. Softmax: per-lane l
// partials (no per-tile sum shuffles), defer-max guard on per-lane local max
// (cross-lane max only on update tiles), cvt_pk bf16 pack.
__global__ __launch_bounds__(512, 4) void flash_k(const u16* __restrict__ qb, const u16* __restrict__ kb,
                                                  const u16* __restrict__ vt, u16* __restrict__ yab) {
    __shared__ u16 Ks[2][64 * 72];
    __shared__ u16 Vs[2][64 * 72];
    __shared__ u16 Ps[8][16 * 72];           // [wave][q-row 16][k' 64 pad 72]
    int tid = threadIdx.x;
    int bx = blockIdx.x, by = blockIdx.y;
    int qt = (by < 16) ? (15 - bx) : bx;      // complementary pairing for balance
    int bh = by;
    int w = tid >> 6, lane = tid & 63, lr = lane & 15, quad = lane >> 4;
    int q0 = qt * 128;
    const u16* qh = qb + (size_t)bh * T_SEQ * HD;
    const u16* kh = kb + (size_t)bh * T_SEQ * HD;
    const u16* vh = vt + (size_t)bh * HD * T_SEQ;

    int rbase = q0 + w * 16;                  // this wave's strip

    s16x8 aq[2];                              // B-frag of Q (n=q-row=lr, k=d)
#pragma unroll
    for (int ks = 0; ks < 2; ++ks)
        aq[ks] = *(const s16x8*)(qh + (size_t)(rbase + lr) * HD + ks * 32 + quad * 8);

    int srow = tid >> 3, sc8 = (tid & 7) << 3;   // staging coords: rows 0..63

    float m_i = -1e30f;
    f32x4 l4 = {0.f, 0.f, 0.f, 0.f};          // per-lane l partials
    f32x4 oacc[4] = {};                       // O^T: elem (d=tn*16+quad*4+r, q=lr)

    int ktmax = 2 * qt + 1;
    {   // prologue: stage tile 0 into buffer 0 (1 K-row + 1 V-row per thread)
        s16x8 kr0 = *(const s16x8*)(kh + (size_t)srow * HD + sc8);
        s16x8 vr0 = *(const s16x8*)(vh + (size_t)srow * T_SEQ + sc8);
        *(s16x8*)&Ks[0][srow * 72 + sc8] = kr0;
        *(s16x8*)&Vs[0][srow * 72 + sc8] = vr0;
    }
    __syncthreads();

    for (int kt = 0; kt <= ktmax; ++kt) {
        int cur = kt & 1;
        int k0 = kt * 64;
        bool pf = kt < ktmax;
        s16x8 kr0, vr0;                       // next-tile prefetch registers
        if (pf) {
            int kn = k0 + 64;
            kr0 = *(const s16x8*)(kh + (size_t)(kn + srow) * HD + sc8);
            vr0 = *(const s16x8*)(vh + (size_t)srow * T_SEQ + kn + sc8);
        }
        const u16* Kc = Ks[cur];
        const u16* Vc = Vs[cur];

        if (k0 <= rbase + 15) {               // strip not fully above diagonal
            s16x8 ak[2][4], av[2][4];         // K frag (m=k-row=lr) / V frag (m=d=lr)
#pragma unroll
            for (int ks = 0; ks < 2; ++ks)
#pragma unroll
                for (int tc = 0; tc < 4; ++tc) {
                    ak[ks][tc] = *(const s16x8*)&Kc[(tc * 16 + lr) * 72 + ks * 32 + quad * 8];
                    av[ks][tc] = *(const s16x8*)&Vc[(tc * 16 + lr) * 72 + ks * 32 + quad * 8];
                }
            f32x4 sacc[4] = {};
#pragma unroll
            for (int ks = 0; ks < 2; ++ks)
#pragma unroll
                for (int tc = 0; tc < 4; ++tc) sacc[tc] = MFMA16(ak[ks][tc], aq[ks], sacc[tc]);
            if (k0 + 63 > rbase) {
#pragma unroll
                for (int tc = 0; tc < 4; ++tc)
#pragma unroll
                    for (int r = 0; r < 4; ++r)
                        if (k0 + tc * 16 + quad * 4 + r > rbase + lr) sacc[tc][r] = -1e30f;
            }
            // per-lane local max (row max = max over 4 lanes; __all is the
            // same condition as the old row-max guard)
            f32x4 mv = sacc[0];
#pragma unroll
            for (int tc = 1; tc < 4; ++tc)
#pragma unroll
                for (int r = 0; r < 4; ++r) mv[r] = fmaxf(mv[r], sacc[tc][r]);
            float loc = fmaxf(fmaxf(mv[0], mv[1]), fmaxf(mv[2], mv[3]));
            bool need = !__all(loc <= m_i + 8.0f);   // defer-max (T13, THR=8)
            float alpha = 1.0f;
            if (need) {                        // rare: full cross-lane max
                float mx = fmaxf(loc, __shfl_xor(loc, 16, 64));
                mx = fmaxf(mx, __shfl_xor(mx, 32, 64));
                float mn = fmaxf(m_i, mx);
                alpha = __builtin_exp2f(m_i - mn);
                m_i = mn;
#pragma unroll
                for (int r = 0; r < 4; ++r) l4[r] *= alpha;
            }
            float mnow = m_i;
#pragma unroll
            for (int tc = 0; tc < 4; ++tc)
#pragma unroll
                for (int r = 0; r < 4; ++r) {
                    float p = __builtin_exp2f(sacc[tc][r] - mnow);
                    sacc[tc][r] = p;
                    l4[r] += p;                // per-lane partial; folded at end
                }
            // P^T -> LDS [q][k'] (cvt_pk packed 8B writes)
#pragma unroll
            for (int tc = 0; tc < 4; ++tc)
                *(u16x4*)&Ps[w][lr * 72 + tc * 16 + quad * 4] = pack4cvt(sacc[tc]);
            if (need) {
#pragma unroll
                for (int tn = 0; tn < 4; ++tn)
#pragma unroll
                    for (int r = 0; r < 4; ++r) oacc[tn][r] *= alpha;
            }
#pragma unroll
            for (int ks = 0; ks < 2; ++ks) {
                s16x8 ap = *(const s16x8*)&Ps[w][lr * 72 + ks * 32 + quad * 8];
#pragma unroll
                for (int tn = 0; tn < 4; ++tn) oacc[tn] = MFMA16(av[ks][tn], ap, oacc[tn]);
            }
        }
        if (pf) {                              // write prefetched tile to other buffer
            int nx = cur ^ 1;
            *(s16x8*)&Ks[nx][srow * 72 + sc8] = kr0;
            *(s16x8*)&Vs[nx][srow * 72 + sc8] = vr0;
        }
        __syncthreads();                       // single barrier per k-tile
    }
    // fold l partials: 4 per-lane + the 4 lanes of each row (xor 16, 32)
    float rs = (l4[0] + l4[1]) + (l4[2] + l4[3]);
    rs += __shfl_xor(rs, 16, 64);
    rs += __shfl_xor(rs, 32, 64);
    int b = bh >> 4, hh = bh & 15;
    {
        float inv = 1.f / rs;
        int t = rbase + lr;
        size_t base = ((size_t)b * T_SEQ + t) * C_EMB + hh * HD;
#pragma unroll
        for (int tn = 0; tn < 4; ++tn) {
            f32x4 vv;
#pragma unroll
            for (int r = 0; r < 4; ++r) vv[r] = oacc[tn][r] * inv;
            *(u16x4*)(yab + base + tn * 16 + quad * 4) = pack4(vv);
        }
    }
}

// ---------------- k3: output projection (MFMA, bf16, gload_lds + XOR swz) --
// grid (8, 32): n0 = bx*128 (0..1023), m0 = by*128
__global__ __launch_bounds__(256) void proj_k(const u16* __restrict__ ya, const u16* __restrict__ Wpb,
                                              const float* __restrict__ bias, float* __restrict__ out) {
    __shared__ u16 As[8192];                  // [128][64] linear (content swizzled)
    __shared__ u16 Bs[8192];
    int tid = threadIdx.x;
    int n0 = blockIdx.x * 128, m0 = blockIdx.y * 128;
    int w = tid >> 6, lane = tid & 63, lr = lane & 15, quad = lane >> 4;
    int wr = w >> 1, wc = w & 1;
    f32x4 acc[4][4] = {};
    int srow = tid >> 3;
    int swc8 = (((tid & 7) ^ (srow & 7)) << 3);           // pre-swizzled src col
    int lrx = lr & 7;
    for (int kt = 0; kt < C_EMB; kt += 64) {
#pragma unroll
        for (int it = 0; it < 4; ++it) {
            int row = it * 32 + srow;
            int off = (it * 256 + tid) * 8;
            gload16(ya + (size_t)(m0 + row) * C_EMB + kt + swc8, &As[off]);
            gload16(Wpb + (size_t)(n0 + row) * C_EMB + kt + swc8, &Bs[off]);
        }
        __syncthreads();
#pragma unroll
        for (int ks = 0; ks < 64; ks += 32) {
            int slot = (ks >> 3) + quad;
            int rc8 = ((slot ^ lrx) << 3);
            s16x8 af[4], bf[4];
#pragma unroll
            for (int i = 0; i < 4; ++i)
                af[i] = *(const s16x8*)&As[(wr * 64 + i * 16 + lr) * 64 + rc8];
#pragma unroll
            for (int j = 0; j < 4; ++j)
                bf[j] = *(const s16x8*)&Bs[(wc * 64 + j * 16 + lr) * 64 + rc8];
#pragma unroll
            for (int i = 0; i < 4; ++i)
#pragma unroll
                for (int j = 0; j < 4; ++j) acc[i][j] = MFMA16(af[i], bf[j], acc[i][j]);
        }
        __syncthreads();
    }
    float bv[4];
#pragma unroll
    for (int j = 0; j < 4; ++j) bv[j] = bias[n0 + wc * 64 + j * 16 + lr];
#pragma unroll
    for (int i = 0; i < 4; ++i)
#pragma unroll
        for (int r = 0; r < 4; ++r) {
            int m = m0 + wr * 64 + i * 16 + quad * 4 + r;
#pragma unroll
            for (int j = 0; j < 4; ++j)
                out[(size_t)m * C_EMB + n0 + wc * 64 + j * 16 + lr] = acc[i][j][r] + bv[j];
        }
}

extern "C" void kernel_launch(void* const* d_in, const int* in_sizes, int n_in,
                              void* d_out, int out_size, void* d_ws, size_t ws_size,
                              hipStream_t stream) {
    // Inputs resolved BY ELEMENT COUNT (unique): x 4194304, W_attn 3145728,
    // b_attn 3072, W_proj 1048576, b_proj 1024. All fp32.
    const float *x = nullptr, *Wa = nullptr, *ba = nullptr, *Wp = nullptr, *bp = nullptr;
    for (int i = 0; i < n_in; ++i) {
        switch (in_sizes[i]) {
            case 4194304: x  = (const float*)d_in[i]; break;
            case 3145728: Wa = (const float*)d_in[i]; break;
            case 3072:    ba = (const float*)d_in[i]; break;
            case 1048576: Wp = (const float*)d_in[i]; break;
            case 1024:    bp = (const float*)d_in[i]; break;
            default: break;
        }
    }
    float* out = (float*)d_out;

    char* ws = (char*)d_ws;
    u16* qb     = (u16*)(ws);                    //  0.. 8 MiB  bf16 [B,H,T,D] (q*0.125*log2e)
    u16* kb     = (u16*)(ws + 8388608);          //  8..16 MiB  bf16 [B,H,T,D]
    u16* vt     = (u16*)(ws + 16777216);         // 16..24 MiB  bf16 [B,H,D,T]
    u16* yab    = (u16*)(ws + 25165824);         // 24..32 MiB  bf16 [B,T,C]
    float2* tab = (float2*)(ws + 33554432);      // 32..32.5 MiB
    u16* xb     = (u16*)(ws + 35651584);         // 34..42 MiB  bf16 [4096,1024]
    u16* Wab    = (u16*)(ws + 44040192);         // 42..48 MiB  bf16 [3072,1024]
    u16* Wpb    = (u16*)(ws + 50331648);         // 48..50 MiB  bf16 [1024,1024]

    conv_k<<<2048, 256, 0, stream>>>(x, xb, 524288);
    conv_k<<<1536, 256, 0, stream>>>(Wa, Wab, 393216);
    conv_k<<<512, 256, 0, stream>>>(Wp, Wpb, 131072);
    rope_tab_k<<<256, 256, 0, stream>>>(tab);
    qkv_rope_k<<<dim3(24, 32), 256, 0, stream>>>(xb, Wab, ba, tab, qb, kb, vt);
    flash_k<<<dim3(16, 32), 512, 0, stream>>>(qb, kb, vt, yab);
    proj_k<<<dim3(8, 32), 256, 0, stream>>>(yab, Wpb, bp, out);
}